// Round 5
// baseline (407.077 us; speedup 1.0000x reference)
//
#include <hip/hip_runtime.h>
#include <hip/hip_bf16.h>
#include <stdint.h>

#define TREES 8192
#define HID   256
#define CH    16
#define KL    4
#define G     4            // trees per block (LDS 33.8 KB -> 4 blocks/CU)
#define LDSS  264          // LDS row stride in bf16 elems (256 + 8 pad)

typedef short bf16x8 __attribute__((ext_vector_type(8)));
typedef float f32x4  __attribute__((ext_vector_type(4)));

__device__ __forceinline__ unsigned short f2bf(float f) {
    unsigned u = __builtin_bit_cast(unsigned, f);
    u += 0x7FFFu + ((u >> 16) & 1u);
    return (unsigned short)(u >> 16);
}
__device__ __forceinline__ float elu1(float x) {
    return x > 0.f ? x : (__expf(x) - 1.f);
}

// ---- Prep A: tiled transpose fp32 [h][d] -> bf16 [d][h], coalesced both sides.
__global__ void prep_transpose(const float* __restrict__ Wz,
                               const float* __restrict__ Wzf,
                               unsigned short* __restrict__ WzT,
                               unsigned short* __restrict__ WzfT) {
    __shared__ unsigned short ts[64][65];
    const int k  = blockIdx.z;
    const int h0 = blockIdx.x * 64;
    const int d0 = blockIdx.y * 64;
    const float* src = (k < KL) ? (Wz + (k << 16)) : Wzf;
    unsigned short* dst = (k < KL) ? (WzT + (k << 16)) : WzfT;
    const int tid = threadIdx.x;
    const int jc  = tid & 63;
    #pragma unroll
    for (int r = 0; r < 16; ++r) {
        int i = r * 4 + (tid >> 6);
        ts[jc][i] = f2bf(src[(h0 + i) * HID + d0 + jc]);
    }
    __syncthreads();
    #pragma unroll
    for (int r = 0; r < 16; ++r) {
        int jl = r * 4 + (tid >> 6);
        dst[(d0 + jl) * HID + h0 + jc] = ts[jl][jc];
    }
}

__global__ void prep_bzsum(const float* __restrict__ bz, float* __restrict__ bzsum) {
    int d = threadIdx.x;
    float s = 0.f;
    #pragma unroll
    for (int k = 0; k < KL; ++k) s += bz[k * HID + d];
    bzsum[d] = s;
}

__global__ __launch_bounds__(256, 4) void ptree_kernel(
    const float* __restrict__ x,               // [N,256] fp32
    const int* __restrict__ leaf,              // [T,16]
    const float* __restrict__ bzf,             // [256] fp32
    const unsigned short* __restrict__ WzT,    // [K][d][h] bf16 (ws)
    const unsigned short* __restrict__ WzfT,   // [d][h] bf16 (ws)
    const float* __restrict__ bzsum,           // [256] f32 (ws)
    float* __restrict__ out,                   // [T,256] fp32
    int nrows)
{
    __shared__ __align__(16) unsigned short sh[G][CH][LDSS];  // 33792 B
    // hs (tree-summed h, G rows x 256) overlays sh after GEMM1 (barrier-protected)
    unsigned short (*hs)[LDSS] = (unsigned short (*)[LDSS])&sh[0][0][0];

    const int tid  = threadIdx.x;
    const int lane = tid & 63;
    const int wave = tid >> 6;
    const int t0   = blockIdx.x * G;
    const int ncol = lane & 15;
    const int quad = lane >> 4;

    // ---- Gather: all leaf indices first (independent), then x-loads in two
    //      wide batches (4 x 32B per lane in flight) to maximize MLP.
    int idxs[8];
    #pragma unroll
    for (int i = 0; i < 8; ++i) {
        int cid = i * 256 + tid;
        int idx = leaf[(t0 + (cid >> 9)) * CH + ((cid >> 5) & 15)];
        idxs[i] = (idx >= 0 && idx < nrows) ? idx : 0;
    }
    #pragma unroll
    for (int b = 0; b < 2; ++b) {
        float4 v0[4], v1[4];
        #pragma unroll
        for (int j = 0; j < 4; ++j) {
            int i = b * 4 + j;
            int ch = (i * 256 + tid) & 31;
            const float* src = x + (size_t)idxs[i] * HID + ch * 8;
            v0[j] = *(const float4*)src;
            v1[j] = *(const float4*)(src + 4);
        }
        #pragma unroll
        for (int j = 0; j < 4; ++j) {
            int i = b * 4 + j;
            int cid = i * 256 + tid;
            int g   = cid >> 9;
            int row = (cid >> 5) & 15;
            int ch  = cid & 31;
            union { uint4 u4; unsigned short s[8]; } U;
            U.s[0] = f2bf(v0[j].x); U.s[1] = f2bf(v0[j].y);
            U.s[2] = f2bf(v0[j].z); U.s[3] = f2bf(v0[j].w);
            U.s[4] = f2bf(v1[j].x); U.s[5] = f2bf(v1[j].y);
            U.s[6] = f2bf(v1[j].z); U.s[7] = f2bf(v1[j].w);
            *(uint4*)&sh[g][row][ch * 8] = U.u4;
        }
    }

    float bzs[4], bzfv[4];
    #pragma unroll
    for (int nt = 0; nt < 4; ++nt) {
        bzs[nt]  = bzsum[wave * 64 + nt * 16 + ncol];
        bzfv[nt] = bzf[wave * 64 + nt * 16 + ncol];
    }

    __syncthreads();

    // ---- GEMM1: rolled_sum[c][d] = sum_k data[(c-k)&15][:] @ Wz[k][:][d]
    f32x4 acc1[G][4];
    #pragma unroll
    for (int g = 0; g < G; ++g)
        #pragma unroll
        for (int nt = 0; nt < 4; ++nt) acc1[g][nt] = f32x4{0.f, 0.f, 0.f, 0.f};

    const unsigned short* wz_base = WzT + (wave * 64 + ncol) * HID + quad * 8;
    bf16x8 bc[4], bn[4];
    #pragma unroll
    for (int nt = 0; nt < 4; ++nt)
        bc[nt] = *(const bf16x8*)(wz_base + nt * 16 * HID);

    #pragma unroll 2
    for (int s = 0; s < KL * 8; ++s) {
        const int sn = (s < KL * 8 - 1) ? s + 1 : s;
        const unsigned short* pn = wz_base + (sn >> 3) * 65536 + (sn & 7) * 32;
        #pragma unroll
        for (int nt = 0; nt < 4; ++nt)
            bn[nt] = *(const bf16x8*)(pn + nt * 16 * HID);
        const int k    = s >> 3;
        const int kt   = s & 7;
        const int arow = (ncol - k) & 15;
        #pragma unroll
        for (int g = 0; g < G; ++g) {
            bf16x8 a = *(const bf16x8*)&sh[g][arow][kt * 32 + quad * 8];
            #pragma unroll
            for (int nt = 0; nt < 4; ++nt)
                acc1[g][nt] = __builtin_amdgcn_mfma_f32_16x16x32_bf16(a, bc[nt], acc1[g][nt], 0, 0, 0);
        }
        #pragma unroll
        for (int nt = 0; nt < 4; ++nt) bc[nt] = bn[nt];
    }

    __syncthreads();   // WAR: sh reads done before hs overlay writes

    // ---- hsum: +bz, ELU, sum 16 children in-register; write G rows to hs.
    #pragma unroll
    for (int g = 0; g < G; ++g)
        #pragma unroll
        for (int nt = 0; nt < 4; ++nt) {
            float s = 0.f;
            #pragma unroll
            for (int r = 0; r < 4; ++r) s += elu1(acc1[g][nt][r] + bzs[nt]);
            s += __shfl_xor(s, 16);
            s += __shfl_xor(s, 32);
            if (quad == 0) hs[g][wave * 64 + nt * 16 + ncol] = f2bf(s);
        }

    __syncthreads();   // RAW: hs visible to all waves

    // ---- GEMM2 (tiny): out[t][d] = elu(hsum[t][:] @ Wzf[:][d] + 16*bzf[d])
    f32x4 acc2[4];
    #pragma unroll
    for (int nt = 0; nt < 4; ++nt) acc2[nt] = f32x4{0.f, 0.f, 0.f, 0.f};

    const unsigned short* wzf_base = WzfT + (wave * 64 + ncol) * HID + quad * 8;
    #pragma unroll 2
    for (int kt = 0; kt < 8; ++kt) {
        bf16x8 a = *(const bf16x8*)&hs[ncol & 3][kt * 32 + quad * 8];
        if (ncol >= G) a = bf16x8{0, 0, 0, 0, 0, 0, 0, 0};
        #pragma unroll
        for (int nt = 0; nt < 4; ++nt) {
            bf16x8 b = *(const bf16x8*)(wzf_base + nt * 16 * HID + kt * 32);
            acc2[nt] = __builtin_amdgcn_mfma_f32_16x16x32_bf16(a, b, acc2[nt], 0, 0, 0);
        }
    }

    // ---- Store: C row = quad*4+r = tree (0..3 valid -> quad 0), col = d.
    if (quad == 0) {
        #pragma unroll
        for (int nt = 0; nt < 4; ++nt)
            #pragma unroll
            for (int r = 0; r < 4; ++r) {
                float v = elu1(acc2[nt][r] + 16.f * bzfv[nt]);
                out[(size_t)(t0 + r) * HID + wave * 64 + nt * 16 + ncol] = v;
            }
    }
}

extern "C" void kernel_launch(void* const* d_in, const int* in_sizes, int n_in,
                              void* d_out, int out_size, void* d_ws, size_t ws_size,
                              hipStream_t stream) {
    (void)out_size; (void)ws_size;
    const void* p_x = nullptr; const void* p_Wz = nullptr; const void* p_bz = nullptr;
    const void* p_Wzf = nullptr; const void* p_bzf = nullptr; const void* p_leaf = nullptr;
    for (int i = 0; i < n_in; ++i) {
        switch (in_sizes[i]) {
            case 200000 * 256:   p_x    = d_in[i]; break;
            case KL * 256 * 256: p_Wz   = d_in[i]; break;
            case KL * 256:       p_bz   = d_in[i]; break;
            case 256 * 256:      p_Wzf  = d_in[i]; break;
            case 256:            p_bzf  = d_in[i]; break;
            case TREES * CH:     p_leaf = d_in[i]; break;
        }
    }
    const float* x    = (const float*)p_x;
    const float* Wz   = (const float*)p_Wz;
    const float* bz   = (const float*)p_bz;
    const float* Wzf  = (const float*)p_Wzf;
    const float* bzf  = (const float*)p_bzf;
    const int*   leaf = (const int*)p_leaf;

    unsigned short* WzT  = (unsigned short*)d_ws;        // 512 KB
    unsigned short* WzfT = WzT + KL * HID * HID;         // 128 KB
    float*          bzsum = (float*)(WzfT + HID * HID);  // 1 KB

    dim3 tg(4, 4, KL + 1);
    prep_transpose<<<tg, 256, 0, stream>>>(Wz, Wzf, WzT, WzfT);
    prep_bzsum<<<1, HID, 0, stream>>>(bz, bzsum);
    ptree_kernel<<<TREES / G, 256, 0, stream>>>(x, leaf, bzf, WzT, WzfT, bzsum,
                                                (float*)d_out, 200000);
}